// Round 11
// baseline (280.480 us; speedup 1.0000x reference)
//
#include <hip/hip_runtime.h>
#include <math.h>

#define NPTS 4096
#define NB   8
#define NC   64
#define KSEL 30
#define NROWS (NB * NPTS * KSEL)   // 983040
#define CNT_F 983040.0f
#define SURVZ 3840                 // pts[SURVZ..4095] overlaid by survivors after tau
#define P23_BLOCKS 960
#define P23_STRIDE (P23_BLOCKS * 256)   // 245760; x4 rows = NROWS

static __device__ __forceinline__ unsigned long long shfl_xor_u64(unsigned long long v, int lx) {
    int lo = __shfl_xor((int)(unsigned)(v & 0xFFFFFFFFULL), lx, 64);
    int hi = __shfl_xor((int)(unsigned)(v >> 32), lx, 64);
    return ((unsigned long long)(unsigned)hi << 32) | (unsigned)lo;
}

// ---------------------------------------------------------------------------
// helpers: per-block reduction of 64-spread accumulator slots, BN param math
// ---------------------------------------------------------------------------
template <int NM>
static __device__ __forceinline__ void slot_reduce(const float* __restrict__ acc,
                                                   float* __restrict__ sSum, int tid) {
    if (tid < 64) {
        float pm[NM];
#pragma unroll
        for (int m = 0; m < NM; ++m) pm[m] = acc[m * 64 + tid];
#pragma unroll
        for (int o = 32; o > 0; o >>= 1) {
#pragma unroll
            for (int m = 0; m < NM; ++m) pm[m] += __shfl_xor(pm[m], o, 64);
        }
        if (tid == 0) {
#pragma unroll
            for (int m = 0; m < NM; ++m) sSum[m] = pm[m];
        }
    }
}

static __device__ __forceinline__ void bn1_params(const float* __restrict__ sSum,
                                                  const float* __restrict__ W1,
                                                  const float* __restrict__ g1,
                                                  const float* __restrict__ b1,
                                                  float* __restrict__ sPar, int tid) {
    if (tid < 6) {
        const float invN = 1.0f / CNT_F;
        const float m0 = sSum[0] * invN, m1 = sSum[1] * invN, m2 = sSum[2] * invN;
        const float E00 = sSum[3] * invN, E01 = sSum[4] * invN, E02 = sSum[5] * invN;
        const float E11 = sSum[6] * invN, E12 = sSum[7] * invN, E22 = sSum[8] * invN;
        const float* w = W1 + tid * 6;
        const float third = (w[3] + w[4] + w[5]) * (1.0f / 3.0f);
        const float a0 = w[0] + w[3] - third;
        const float a1 = w[1] + w[4] - third;
        const float a2 = w[2] + w[5] - third;
        const float mu = a0 * m0 + a1 * m1 + a2 * m2;
        const float E2 = a0 * a0 * E00 + a1 * a1 * E11 + a2 * a2 * E22 +
                         2.0f * (a0 * a1 * E01 + a0 * a2 * E02 + a1 * a2 * E12);
        const float var = E2 - mu * mu;
        const float sc = g1[tid] / sqrtf(var + 1e-5f);
        sPar[tid] = sc;
        sPar[6 + tid] = b1[tid] - mu * sc;
    }
}

static __device__ __forceinline__ void bn2_params(const float* __restrict__ sSum,
                                                  const float* __restrict__ W2,
                                                  const float* __restrict__ g2,
                                                  const float* __restrict__ b2,
                                                  float* __restrict__ sPar, int tid) {
    if (tid < 3) {
        const float invN = 1.0f / CNT_F;
        float Eh[6];
#pragma unroll
        for (int d = 0; d < 6; ++d) Eh[d] = sSum[d] * invN;
        float M[6][6];
        int q = 6;
#pragma unroll
        for (int a2 = 0; a2 < 6; ++a2)
#pragma unroll
            for (int b2_ = a2; b2_ < 6; ++b2_) {
                const float v = sSum[q++] * invN;
                M[a2][b2_] = v; M[b2_][a2] = v;
            }
        const float* w = W2 + tid * 6;
        float mu = 0.0f;
#pragma unroll
        for (int d = 0; d < 6; ++d) mu += w[d] * Eh[d];
        float E2 = 0.0f;
#pragma unroll
        for (int a2 = 0; a2 < 6; ++a2)
#pragma unroll
            for (int b2_ = 0; b2_ < 6; ++b2_) E2 += w[a2] * w[b2_] * M[a2][b2_];
        const float var = E2 - mu * mu;
        const float sc = g2[tid] / sqrtf(var + 1e-5f);
        sPar[12 + tid] = sc;
        sPar[15 + tid] = b2[tid] - mu * sc;
    }
}

static __device__ __forceinline__ void bn3_params(const float* __restrict__ sSum,
                                                  const float* __restrict__ W3,
                                                  const float* __restrict__ g3,
                                                  const float* __restrict__ b3,
                                                  float* __restrict__ sPar, int tid) {
    if (tid == 0) {
        const float invN = 1.0f / CNT_F;
        const float Eh0 = sSum[0] * invN, Eh1 = sSum[1] * invN, Eh2 = sSum[2] * invN;
        const float M00 = sSum[3] * invN, M01 = sSum[4] * invN, M02 = sSum[5] * invN;
        const float M11 = sSum[6] * invN, M12 = sSum[7] * invN, M22 = sSum[8] * invN;
        const float w0 = W3[0], w1 = W3[1], w2 = W3[2];
        const float mu = w0 * Eh0 + w1 * Eh1 + w2 * Eh2;
        const float E2 = w0 * w0 * M00 + w1 * w1 * M11 + w2 * w2 * M22 +
                         2.0f * (w0 * w1 * M01 + w0 * w2 * M02 + w1 * w2 * M12);
        const float var = E2 - mu * mu;
        const float sc = g3[0] / sqrtf(var + 1e-5f);
        sPar[0] = sc;
        sPar[1] = b3[0] - mu * sc;
    }
}

static __device__ __forceinline__ void mlp_h1(float s0, float s1, float s2,
                                              const float* __restrict__ W1,
                                              const float* __restrict__ sPar,
                                              float* __restrict__ h1) {
    const float mean = (s0 + s1 + s2) * (1.0f / 3.0f);
    const float f[6] = {s0, s1, s2, s0 - mean, s1 - mean, s2 - mean};
#pragma unroll
    for (int c = 0; c < 6; ++c) {
        float a = 0.0f;
#pragma unroll
        for (int d = 0; d < 6; ++d) a = fmaf(W1[c * 6 + d], f[d], a);
        const float z = fmaf(a, sPar[c], sPar[6 + c]);
        h1[c] = z >= 0.0f ? z : 0.2f * z;
    }
}

static __device__ __forceinline__ void mlp_h2(const float* __restrict__ h1,
                                              const float* __restrict__ W2,
                                              const float* __restrict__ sPar,
                                              float* __restrict__ h2) {
#pragma unroll
    for (int c = 0; c < 3; ++c) {
        float a = 0.0f;
#pragma unroll
        for (int d = 0; d < 6; ++d) a = fmaf(W2[c * 6 + d], h1[d], a);
        const float z = fmaf(a, sPar[12 + c], sPar[15 + c]);
        h2[c] = z >= 0.0f ? z : 0.2f * z;
    }
}

// ---------------------------------------------------------------------------
// Kernel 1: exact KNN + sph/moment tail. R7-EXACT codegen (proven 120us),
// with a batch offset b0 so the grid can be split into two dispatches
// (diagnostic: halves knn's per-dispatch time so epilogue kernels surface
// in the rocprof top-5).
// ---------------------------------------------------------------------------
__global__ __launch_bounds__(512, 4) void knn_k(const float* __restrict__ xloc,
                                                int* __restrict__ idx_out,
                                                float* __restrict__ sph,   // [3][NROWS]
                                                float* __restrict__ accM,
                                                int b0) {
    __shared__ float4 pts[NPTS];   // exactly 64KB
    __shared__ float msc[72];      // 8 waves x 9 moment partials

    const int tid  = threadIdx.x;
    const int lane = tid & 63;
    const int wv   = tid >> 6;
    const int b    = b0 + blockIdx.y;
    const int n    = (blockIdx.x << 3) + wv;

    const float* xb = xloc + (size_t)b * (3 * NPTS);
    for (int i = tid; i < NPTS; i += 512) {
        const float x = xb[i], y = xb[NPTS + i], z = xb[2 * NPTS + i];
        const float xx = __fadd_rn(__fadd_rn(__fmul_rn(x, x), __fmul_rn(y, y)), __fmul_rn(z, z));
        pts[i] = make_float4(x, y, z, xx);
    }
    __syncthreads();

    const float4 q = pts[n];

    unsigned K[64];
    unsigned lm = 0;
#pragma unroll
    for (int t = 0; t < 64; ++t) {
        const float4 c = pts[lane + (t << 6)];
        const float dt = __fadd_rn(__fadd_rn(__fmul_rn(q.x, c.x), __fmul_rn(q.y, c.y)), __fmul_rn(q.z, c.z));
        const float pd = __fsub_rn(__fsub_rn(__fmul_rn(2.0f, dt), q.w), c.w);
        const unsigned u = __float_as_uint(pd);
        const unsigned key = u ^ ((unsigned)((int)u >> 31) | 0x80000000u);
        K[t] = key;
        lm = key > lm ? key : lm;
    }

    unsigned v = lm;
#pragma unroll
    for (int k = 2; k <= 64; k <<= 1) {
#pragma unroll
        for (int j2 = k >> 1; j2 > 0; j2 >>= 1) {
            const unsigned o = (unsigned)__shfl_xor((int)v, j2, 64);
            const bool keepmax = ((lane & j2) == 0) == ((lane & k) == 0);
            const unsigned mx = v > o ? v : o;
            const unsigned mn = v > o ? o : v;
            v = keepmax ? mx : mn;
        }
    }
    const unsigned tau = (unsigned)__shfl((int)v, 30, 64);

    __syncthreads();

    unsigned long long* surv = ((unsigned long long*)(pts + SURVZ)) + (wv << 6);
    surv[lane] = 0ULL;

    unsigned total = 0;
#pragma unroll
    for (int t = 0; t < 64; ++t) {
        const bool p = (K[t] >= tau);
        const unsigned long long m = __ballot(p);
        if (p) {
            const unsigned pos = total + (unsigned)__popcll(m & ((1ULL << lane) - 1ULL));
            if (pos < 64u) {
                const unsigned j = (unsigned)(lane + (t << 6));
                surv[pos] = ((unsigned long long)K[t] << 32) | (unsigned)(~j);
            }
        }
        total += (unsigned)__popcll(m);
    }
    __threadfence_block();

    const int bn = (b << 12) + n;
    const size_t obase = (size_t)bn * KSEL;
    int jn = 0;

    if (total <= 64u) {
        unsigned long long s = surv[lane];
#pragma unroll
        for (int k = 2; k <= 64; k <<= 1) {
#pragma unroll
            for (int j2 = k >> 1; j2 > 0; j2 >>= 1) {
                const unsigned long long o = shfl_xor_u64(s, j2);
                const bool keepmax = ((lane & j2) == 0) == ((lane & k) == 0);
                const unsigned long long mx = s > o ? s : o;
                const unsigned long long mn = s > o ? o : s;
                s = keepmax ? mx : mn;
            }
        }
        jn = (int)(~(unsigned)s) & (NPTS - 1);
        if (lane >= KSEL) jn = 0;
    } else {
        unsigned P = 0;
        for (int bit = 31; bit >= 0; --bit) {
            const unsigned cand = P | (1u << bit);
            int c = 0;
#pragma unroll
            for (int t = 0; t < 64; ++t) c += (K[t] >= cand) ? 1 : 0;
#pragma unroll
            for (int o = 32; o > 0; o >>= 1) c += __shfl_xor(c, o, 64);
            if (c >= KSEL) P = cand;
        }
        int* sj = (int*)surv;
        int emitted = 0;
#pragma unroll
        for (int t = 0; t < 64; ++t) {
            const bool g = (K[t] > P);
            const unsigned long long m = __ballot(g);
            if (g) {
                const int pos = emitted + (int)__popcll(m & ((1ULL << lane) - 1ULL));
                if (pos < KSEL) sj[pos] = lane + (t << 6);
            }
            emitted += (int)__popcll(m);
        }
#pragma unroll
        for (int t = 0; t < 64; ++t) {
            const bool e_ = (K[t] == P);
            const unsigned long long m = __ballot(e_);
            const int before = (int)__popcll(m & ((1ULL << lane) - 1ULL));
            if (e_ && (emitted + before) < KSEL) sj[emitted + before] = lane + (t << 6);
            emitted += (int)__popcll(m);
        }
        __threadfence_block();
        if (lane < KSEL) jn = sj[lane];
    }

    float s0 = 0.0f, s1 = 0.0f, s2 = 0.0f;
    if (lane < KSEL) {
        idx_out[obase + lane] = jn;
        float cx, cy, cz;
        if (jn >= SURVZ) {
            cx = xb[jn]; cy = xb[NPTS + jn]; cz = xb[2 * NPTS + jn];
        } else {
            const float4 c = pts[jn];
            cx = c.x; cy = c.y; cz = c.z;
        }
        const float xr = cx - q.x, yr = cy - q.y, zr = cz - q.z;
        const float sxy2 = xr * xr + yr * yr;
        const float r2   = sxy2 + zr * zr;
        const float rho  = sqrtf(fmaxf(r2, 1e-20f));
        const float sxy  = sqrtf(fmaxf(sxy2, 1e-20f));
        const bool dr = r2 < 1e-20f;
        const bool dp = sxy2 < 1e-20f;
        const float theta = atan2f(dr ? 0.0f : zr, dr ? 1.0f : sxy);
        const float phi   = atan2f(dp ? 0.0f : yr, dp ? 1.0f : xr);
        sph[obase + lane]             = rho;
        sph[NROWS + obase + lane]     = theta;
        sph[2 * NROWS + obase + lane] = phi;
        s0 = rho; s1 = theta; s2 = phi;
    }

    float mom[9] = {s0, s1, s2, s0 * s0, s0 * s1, s0 * s2, s1 * s1, s1 * s2, s2 * s2};
#pragma unroll
    for (int o = 32; o > 0; o >>= 1) {
#pragma unroll
        for (int m = 0; m < 9; ++m) mom[m] += __shfl_xor(mom[m], o, 64);
    }
    if (lane == 0) {
#pragma unroll
        for (int m = 0; m < 9; ++m) msc[wv * 9 + m] = mom[m];
    }
    __syncthreads();
    if (tid < 9) {
        float t_ = 0.0f;
#pragma unroll
        for (int w = 0; w < 8; ++w) t_ += msc[w * 9 + tid];
        atomicAdd(&accM[tid * 64 + ((b * 512 + blockIdx.x) & 63)], t_);
    }
}

// ---------------------------------------------------------------------------
// Kernel 2: h1 moments (27), grid-stride 4 rows/thread; first 512 blocks also
// transpose x [B,C,N] -> xT [B,N,C].  (R9-exact)
// ---------------------------------------------------------------------------
__global__ __launch_bounds__(256) void p2_k(const float* __restrict__ sph,
                                            const float* __restrict__ x,
                                            float* __restrict__ xT,
                                            const float* __restrict__ W1,
                                            const float* __restrict__ g1,
                                            const float* __restrict__ b1,
                                            const float* __restrict__ accM,
                                            float* __restrict__ acc2) {
    __shared__ float sSum[9];
    __shared__ float sPar[12];
    __shared__ float red[4][27];
    __shared__ float tile[64][65];
    const int tid = threadIdx.x;
    slot_reduce<9>(accM, sSum, tid);
    __syncthreads();
    bn1_params(sSum, W1, g1, b1, sPar, tid);
    __syncthreads();

    float m27[27];
#pragma unroll
    for (int m = 0; m < 27; ++m) m27[m] = 0.0f;
#pragma unroll
    for (int s = 0; s < 4; ++s) {
        const size_t r = (size_t)blockIdx.x * 256 + tid + (size_t)s * P23_STRIDE;
        const float s0 = sph[r], s1 = sph[NROWS + r], s2 = sph[2 * NROWS + r];
        float h1[6];
        mlp_h1(s0, s1, s2, W1, sPar, h1);
        int qq = 6;
#pragma unroll
        for (int a2 = 0; a2 < 6; ++a2) {
            m27[a2] += h1[a2];
#pragma unroll
            for (int b2_ = a2; b2_ < 6; ++b2_) m27[qq++] += h1[a2] * h1[b2_];
        }
    }
#pragma unroll
    for (int o = 32; o > 0; o >>= 1) {
#pragma unroll
        for (int m = 0; m < 27; ++m) m27[m] += __shfl_xor(m27[m], o, 64);
    }
    const int lane = tid & 63, wv = tid >> 6;
    if (lane == 0) {
#pragma unroll
        for (int m = 0; m < 27; ++m) red[wv][m] = m27[m];
    }
    __syncthreads();
    if (tid < 27) {
        const float v = red[0][tid] + red[1][tid] + red[2][tid] + red[3][tid];
        atomicAdd(&acc2[tid * 64 + (blockIdx.x & 63)], v);
    }

    if (blockIdx.x < 512) {
        const int b  = blockIdx.x >> 6;
        const int n0 = (blockIdx.x & 63) << 6;
        const int tx = tid & 63;
        const int ty = tid >> 6;
        const float* xb = x + ((size_t)b << 18);
#pragma unroll
        for (int i = 0; i < 16; ++i) {
            const int c = (i << 2) + ty;
            tile[c][tx] = xb[((size_t)c << 12) + n0 + tx];
        }
        __syncthreads();
        float* ob = xT + ((size_t)b << 18);
#pragma unroll
        for (int i = 0; i < 16; ++i) {
            const int nl = (i << 2) + ty;
            ob[((size_t)(n0 + nl) << 6) + tx] = tile[tx][nl];
        }
    }
}

// ---------------------------------------------------------------------------
// Kernel 3: h2 moments (9) + y3 = W3.h2 store, grid-stride 4 rows/thread.
// (R9-exact)
// ---------------------------------------------------------------------------
__global__ __launch_bounds__(256) void p3_k(const float* __restrict__ sph,
                                            const float* __restrict__ W1,
                                            const float* __restrict__ g1,
                                            const float* __restrict__ b1,
                                            const float* __restrict__ W2,
                                            const float* __restrict__ g2,
                                            const float* __restrict__ b2,
                                            const float* __restrict__ W3,
                                            const float* __restrict__ accM,
                                            const float* __restrict__ acc2,
                                            float* __restrict__ acc3,
                                            float* __restrict__ y3) {
    __shared__ float sSum[27];
    __shared__ float sPar[18];
    __shared__ float red[4][9];
    const int tid = threadIdx.x;
    slot_reduce<9>(accM, sSum, tid);
    __syncthreads();
    bn1_params(sSum, W1, g1, b1, sPar, tid);
    __syncthreads();
    slot_reduce<27>(acc2, sSum, tid);
    __syncthreads();
    bn2_params(sSum, W2, g2, b2, sPar, tid);
    __syncthreads();

    const float w30 = W3[0], w31 = W3[1], w32 = W3[2];

    float m9[9];
#pragma unroll
    for (int m = 0; m < 9; ++m) m9[m] = 0.0f;
#pragma unroll
    for (int s = 0; s < 4; ++s) {
        const size_t r = (size_t)blockIdx.x * 256 + tid + (size_t)s * P23_STRIDE;
        const float s0 = sph[r], s1 = sph[NROWS + r], s2 = sph[2 * NROWS + r];
        float h1[6], h2[3];
        mlp_h1(s0, s1, s2, W1, sPar, h1);
        mlp_h2(h1, W2, sPar, h2);
        y3[r] = fmaf(w30, h2[0], fmaf(w31, h2[1], w32 * h2[2]));
        m9[0] += h2[0]; m9[1] += h2[1]; m9[2] += h2[2];
        m9[3] += h2[0] * h2[0]; m9[4] += h2[0] * h2[1]; m9[5] += h2[0] * h2[2];
        m9[6] += h2[1] * h2[1]; m9[7] += h2[1] * h2[2]; m9[8] += h2[2] * h2[2];
    }
#pragma unroll
    for (int o = 32; o > 0; o >>= 1) {
#pragma unroll
        for (int m = 0; m < 9; ++m) m9[m] += __shfl_xor(m9[m], o, 64);
    }
    const int lane = tid & 63, wv = tid >> 6;
    if (lane == 0) {
#pragma unroll
        for (int m = 0; m < 9; ++m) red[wv][m] = m9[m];
    }
    __syncthreads();
    if (tid < 9) {
        const float v = red[0][tid] + red[1][tid] + red[2][tid] + red[3][tid];
        atomicAdd(&acc3[tid * 64 + (blockIdx.x & 63)], v);
    }
}

// ---------------------------------------------------------------------------
// Kernel 4: att = lrelu(BN3(y3)), softmax, gather, residual out. (R9-exact)
// ---------------------------------------------------------------------------
__global__ __launch_bounds__(256) void p4_k(const float* __restrict__ y3,
                                            const int* __restrict__ idx,
                                            const float* __restrict__ x,
                                            const float* __restrict__ xT,
                                            const float* __restrict__ W3,
                                            const float* __restrict__ g3,
                                            const float* __restrict__ b3,
                                            const float* __restrict__ acc3,
                                            float* __restrict__ out) {
    __shared__ float sSum[9];
    __shared__ float sPar[2];
    __shared__ float agg[32][65];
    const int tid = threadIdx.x;
    slot_reduce<9>(acc3, sSum, tid);
    __syncthreads();
    bn3_params(sSum, W3, g3, b3, sPar, tid);
    __syncthreads();
    const float sc3 = sPar[0], tb3 = sPar[1];

    const int lane = tid & 63, wv = tid >> 6;
    const int b    = blockIdx.x & 7;         // XCD swizzle: one batch per XCD
    const int n0   = (blockIdx.x >> 3) << 5; // 32 consecutive points within batch
    const int p0   = (b << 12) + n0;
    const float* xTb = xT + ((size_t)b << 18);

    for (int i = 0; i < 8; ++i) {
        const int pl = (wv << 3) + i;
        const int p  = p0 + pl;
        float a = -3.4e38f;
        int jn = 0;
        if (lane < KSEL) {
            const size_t r = (size_t)p * KSEL + lane;
            const float z = fmaf(y3[r], sc3, tb3);
            a = z >= 0.0f ? z : 0.2f * z;
            jn = idx[r];
        }
        float mx = a;
#pragma unroll
        for (int o = 32; o > 0; o >>= 1) mx = fmaxf(mx, __shfl_xor(mx, o, 64));
        const float e = (lane < KSEL) ? expf(a - mx) : 0.0f;
        float se = e;
#pragma unroll
        for (int o = 32; o > 0; o >>= 1) se += __shfl_xor(se, o, 64);
        const float w = e / se;

        float acc0 = 0.0f, acc1 = 0.0f;
#pragma unroll
        for (int t = 0; t < KSEL; t += 2) {
            const int   j0 = __shfl(jn, t, 64);
            const float w0 = __shfl(w, t, 64);
            const int   j1 = __shfl(jn, t + 1, 64);
            const float w1 = __shfl(w, t + 1, 64);
            acc0 = fmaf(w0, xTb[((size_t)j0 << 6) + lane], acc0);
            acc1 = fmaf(w1, xTb[((size_t)j1 << 6) + lane], acc1);
        }
        agg[pl][lane] = acc0 + acc1;
    }
    __syncthreads();

    const float* xb = x + ((size_t)b << 18);
    float* ob = out + ((size_t)b << 18);
    const int nl = tid & 31, cb = tid >> 5;
#pragma unroll
    for (int i = 0; i < 8; ++i) {
        const int c = (i << 3) + cb;
        const size_t off = ((size_t)c << 12) + n0 + nl;
        ob[off] = xb[off] + agg[nl][c];
    }
}

// ---------------------------------------------------------------------------
extern "C" void kernel_launch(void* const* d_in, const int* in_sizes, int n_in,
                              void* d_out, int out_size, void* d_ws, size_t ws_size,
                              hipStream_t stream) {
    const float* x_loc = (const float*)d_in[0];
    const float* x     = (const float*)d_in[1];
    const float* W1    = (const float*)d_in[2];
    const float* g1    = (const float*)d_in[3];
    const float* b1    = (const float*)d_in[4];
    const float* W2    = (const float*)d_in[5];
    const float* g2    = (const float*)d_in[6];
    const float* b2    = (const float*)d_in[7];
    const float* W3    = (const float*)d_in[8];
    const float* g3    = (const float*)d_in[9];
    const float* b3    = (const float*)d_in[10];
    float* out = (float*)d_out;

    float* accM = (float*)d_ws;                 //  9*64
    float* acc2 = accM + 576;                   // 27*64
    float* acc3 = acc2 + 1728;                  //  9*64  (acc region = 2880 floats)
    float* sph  = acc3 + 576;                   // 3*NROWS
    int*   idx  = (int*)(sph + 3 * (size_t)NROWS);
    float* y3   = (float*)(idx + NROWS);        // NROWS
    float* xT   = y3 + NROWS;                   // B*N*C

    hipMemsetAsync(d_ws, 0, 11520, stream);

    // knn split into two half-grid dispatches (diagnostic: expose epilogue in top-5)
    knn_k<<<dim3(NPTS / 8, NB / 2), 512, 0, stream>>>(x_loc, idx, sph, accM, 0);
    knn_k<<<dim3(NPTS / 8, NB / 2), 512, 0, stream>>>(x_loc, idx, sph, accM, NB / 2);
    p2_k<<<P23_BLOCKS, 256, 0, stream>>>(sph, x, xT, W1, g1, b1, accM, acc2);
    p3_k<<<P23_BLOCKS, 256, 0, stream>>>(sph, W1, g1, b1, W2, g2, b2, W3, accM, acc2, acc3, y3);
    p4_k<<<(NB * NPTS) / 32, 256, 0, stream>>>(y3, idx, x, xT, W3, g3, b3, acc3, out);
}

// Round 12
// 254.431 us; speedup vs baseline: 1.1024x; 1.1024x over previous
//
#include <hip/hip_runtime.h>
#include <math.h>

#define NPTS 4096
#define NB   8
#define NC   64
#define KSEL 30
#define NROWS (NB * NPTS * KSEL)   // 983040
#define CNT_F 983040.0f
#define SURVZ 3840                 // pts[SURVZ..4095] overlaid by survivors after tau
#define P23_BLOCKS 960
#define P23_STRIDE (P23_BLOCKS * 256)   // 245760; x4 rows = NROWS

static __device__ __forceinline__ unsigned long long shfl_xor_u64(unsigned long long v, int lx) {
    int lo = __shfl_xor((int)(unsigned)(v & 0xFFFFFFFFULL), lx, 64);
    int hi = __shfl_xor((int)(unsigned)(v >> 32), lx, 64);
    return ((unsigned long long)(unsigned)hi << 32) | (unsigned)lo;
}

// ---------------------------------------------------------------------------
// helpers: per-block reduction of 64-spread accumulator slots, BN param math
// ---------------------------------------------------------------------------
template <int NM>
static __device__ __forceinline__ void slot_reduce(const float* __restrict__ acc,
                                                   float* __restrict__ sSum, int tid) {
    if (tid < 64) {
        float pm[NM];
#pragma unroll
        for (int m = 0; m < NM; ++m) pm[m] = acc[m * 64 + tid];
#pragma unroll
        for (int o = 32; o > 0; o >>= 1) {
#pragma unroll
            for (int m = 0; m < NM; ++m) pm[m] += __shfl_xor(pm[m], o, 64);
        }
        if (tid == 0) {
#pragma unroll
            for (int m = 0; m < NM; ++m) sSum[m] = pm[m];
        }
    }
}

static __device__ __forceinline__ void bn1_params(const float* __restrict__ sSum,
                                                  const float* __restrict__ W1,
                                                  const float* __restrict__ g1,
                                                  const float* __restrict__ b1,
                                                  float* __restrict__ sPar, int tid) {
    if (tid < 6) {
        const float invN = 1.0f / CNT_F;
        const float m0 = sSum[0] * invN, m1 = sSum[1] * invN, m2 = sSum[2] * invN;
        const float E00 = sSum[3] * invN, E01 = sSum[4] * invN, E02 = sSum[5] * invN;
        const float E11 = sSum[6] * invN, E12 = sSum[7] * invN, E22 = sSum[8] * invN;
        const float* w = W1 + tid * 6;
        const float third = (w[3] + w[4] + w[5]) * (1.0f / 3.0f);
        const float a0 = w[0] + w[3] - third;
        const float a1 = w[1] + w[4] - third;
        const float a2 = w[2] + w[5] - third;
        const float mu = a0 * m0 + a1 * m1 + a2 * m2;
        const float E2 = a0 * a0 * E00 + a1 * a1 * E11 + a2 * a2 * E22 +
                         2.0f * (a0 * a1 * E01 + a0 * a2 * E02 + a1 * a2 * E12);
        const float var = E2 - mu * mu;
        const float sc = g1[tid] / sqrtf(var + 1e-5f);
        sPar[tid] = sc;
        sPar[6 + tid] = b1[tid] - mu * sc;
    }
}

static __device__ __forceinline__ void bn2_params(const float* __restrict__ sSum,
                                                  const float* __restrict__ W2,
                                                  const float* __restrict__ g2,
                                                  const float* __restrict__ b2,
                                                  float* __restrict__ sPar, int tid) {
    if (tid < 3) {
        const float invN = 1.0f / CNT_F;
        float Eh[6];
#pragma unroll
        for (int d = 0; d < 6; ++d) Eh[d] = sSum[d] * invN;
        float M[6][6];
        int q = 6;
#pragma unroll
        for (int a2 = 0; a2 < 6; ++a2)
#pragma unroll
            for (int b2_ = a2; b2_ < 6; ++b2_) {
                const float v = sSum[q++] * invN;
                M[a2][b2_] = v; M[b2_][a2] = v;
            }
        const float* w = W2 + tid * 6;
        float mu = 0.0f;
#pragma unroll
        for (int d = 0; d < 6; ++d) mu += w[d] * Eh[d];
        float E2 = 0.0f;
#pragma unroll
        for (int a2 = 0; a2 < 6; ++a2)
#pragma unroll
            for (int b2_ = 0; b2_ < 6; ++b2_) E2 += w[a2] * w[b2_] * M[a2][b2_];
        const float var = E2 - mu * mu;
        const float sc = g2[tid] / sqrtf(var + 1e-5f);
        sPar[12 + tid] = sc;
        sPar[15 + tid] = b2[tid] - mu * sc;
    }
}

static __device__ __forceinline__ void bn3_params(const float* __restrict__ sSum,
                                                  const float* __restrict__ W3,
                                                  const float* __restrict__ g3,
                                                  const float* __restrict__ b3,
                                                  float* __restrict__ sPar, int tid) {
    if (tid == 0) {
        const float invN = 1.0f / CNT_F;
        const float Eh0 = sSum[0] * invN, Eh1 = sSum[1] * invN, Eh2 = sSum[2] * invN;
        const float M00 = sSum[3] * invN, M01 = sSum[4] * invN, M02 = sSum[5] * invN;
        const float M11 = sSum[6] * invN, M12 = sSum[7] * invN, M22 = sSum[8] * invN;
        const float w0 = W3[0], w1 = W3[1], w2 = W3[2];
        const float mu = w0 * Eh0 + w1 * Eh1 + w2 * Eh2;
        const float E2 = w0 * w0 * M00 + w1 * w1 * M11 + w2 * w2 * M22 +
                         2.0f * (w0 * w1 * M01 + w0 * w2 * M02 + w1 * w2 * M12);
        const float var = E2 - mu * mu;
        const float sc = g3[0] / sqrtf(var + 1e-5f);
        sPar[0] = sc;
        sPar[1] = b3[0] - mu * sc;
    }
}

static __device__ __forceinline__ void mlp_h1(float s0, float s1, float s2,
                                              const float* __restrict__ W1,
                                              const float* __restrict__ sPar,
                                              float* __restrict__ h1) {
    const float mean = (s0 + s1 + s2) * (1.0f / 3.0f);
    const float f[6] = {s0, s1, s2, s0 - mean, s1 - mean, s2 - mean};
#pragma unroll
    for (int c = 0; c < 6; ++c) {
        float a = 0.0f;
#pragma unroll
        for (int d = 0; d < 6; ++d) a = fmaf(W1[c * 6 + d], f[d], a);
        const float z = fmaf(a, sPar[c], sPar[6 + c]);
        h1[c] = z >= 0.0f ? z : 0.2f * z;
    }
}

static __device__ __forceinline__ void mlp_h2(const float* __restrict__ h1,
                                              const float* __restrict__ W2,
                                              const float* __restrict__ sPar,
                                              float* __restrict__ h2) {
#pragma unroll
    for (int c = 0; c < 3; ++c) {
        float a = 0.0f;
#pragma unroll
        for (int d = 0; d < 6; ++d) a = fmaf(W2[c * 6 + d], h1[d], a);
        const float z = fmaf(a, sPar[12 + c], sPar[15 + c]);
        h2[c] = z >= 0.0f ? z : 0.2f * z;
    }
}

// ---------------------------------------------------------------------------
// Kernel 1: exact KNN + sph/moment tail. R7-EXACT (proven 120us, no spill).
// Single full-grid dispatch (R11 split measured -48us penalty; reverted).
// ---------------------------------------------------------------------------
__global__ __launch_bounds__(512, 4) void knn_k(const float* __restrict__ xloc,
                                                int* __restrict__ idx_out,
                                                float* __restrict__ sph,   // [3][NROWS]
                                                float* __restrict__ accM) {
    __shared__ float4 pts[NPTS];   // exactly 64KB
    __shared__ float msc[72];      // 8 waves x 9 moment partials

    const int tid  = threadIdx.x;
    const int lane = tid & 63;
    const int wv   = tid >> 6;
    const int b    = blockIdx.y;
    const int n    = (blockIdx.x << 3) + wv;

    const float* xb = xloc + (size_t)b * (3 * NPTS);
    for (int i = tid; i < NPTS; i += 512) {
        const float x = xb[i], y = xb[NPTS + i], z = xb[2 * NPTS + i];
        const float xx = __fadd_rn(__fadd_rn(__fmul_rn(x, x), __fmul_rn(y, y)), __fmul_rn(z, z));
        pts[i] = make_float4(x, y, z, xx);
    }
    __syncthreads();

    const float4 q = pts[n];

    unsigned K[64];
    unsigned lm = 0;
#pragma unroll
    for (int t = 0; t < 64; ++t) {
        const float4 c = pts[lane + (t << 6)];
        const float dt = __fadd_rn(__fadd_rn(__fmul_rn(q.x, c.x), __fmul_rn(q.y, c.y)), __fmul_rn(q.z, c.z));
        const float pd = __fsub_rn(__fsub_rn(__fmul_rn(2.0f, dt), q.w), c.w);
        const unsigned u = __float_as_uint(pd);
        const unsigned key = u ^ ((unsigned)((int)u >> 31) | 0x80000000u);
        K[t] = key;
        lm = key > lm ? key : lm;
    }

    unsigned v = lm;
#pragma unroll
    for (int k = 2; k <= 64; k <<= 1) {
#pragma unroll
        for (int j2 = k >> 1; j2 > 0; j2 >>= 1) {
            const unsigned o = (unsigned)__shfl_xor((int)v, j2, 64);
            const bool keepmax = ((lane & j2) == 0) == ((lane & k) == 0);
            const unsigned mx = v > o ? v : o;
            const unsigned mn = v > o ? o : v;
            v = keepmax ? mx : mn;
        }
    }
    const unsigned tau = (unsigned)__shfl((int)v, 30, 64);

    __syncthreads();

    unsigned long long* surv = ((unsigned long long*)(pts + SURVZ)) + (wv << 6);
    surv[lane] = 0ULL;

    unsigned total = 0;
#pragma unroll
    for (int t = 0; t < 64; ++t) {
        const bool p = (K[t] >= tau);
        const unsigned long long m = __ballot(p);
        if (p) {
            const unsigned pos = total + (unsigned)__popcll(m & ((1ULL << lane) - 1ULL));
            if (pos < 64u) {
                const unsigned j = (unsigned)(lane + (t << 6));
                surv[pos] = ((unsigned long long)K[t] << 32) | (unsigned)(~j);
            }
        }
        total += (unsigned)__popcll(m);
    }
    __threadfence_block();

    const int bn = (b << 12) + n;
    const size_t obase = (size_t)bn * KSEL;
    int jn = 0;

    if (total <= 64u) {
        unsigned long long s = surv[lane];
#pragma unroll
        for (int k = 2; k <= 64; k <<= 1) {
#pragma unroll
            for (int j2 = k >> 1; j2 > 0; j2 >>= 1) {
                const unsigned long long o = shfl_xor_u64(s, j2);
                const bool keepmax = ((lane & j2) == 0) == ((lane & k) == 0);
                const unsigned long long mx = s > o ? s : o;
                const unsigned long long mn = s > o ? o : s;
                s = keepmax ? mx : mn;
            }
        }
        jn = (int)(~(unsigned)s) & (NPTS - 1);
        if (lane >= KSEL) jn = 0;
    } else {
        unsigned P = 0;
        for (int bit = 31; bit >= 0; --bit) {
            const unsigned cand = P | (1u << bit);
            int c = 0;
#pragma unroll
            for (int t = 0; t < 64; ++t) c += (K[t] >= cand) ? 1 : 0;
#pragma unroll
            for (int o = 32; o > 0; o >>= 1) c += __shfl_xor(c, o, 64);
            if (c >= KSEL) P = cand;
        }
        int* sj = (int*)surv;
        int emitted = 0;
#pragma unroll
        for (int t = 0; t < 64; ++t) {
            const bool g = (K[t] > P);
            const unsigned long long m = __ballot(g);
            if (g) {
                const int pos = emitted + (int)__popcll(m & ((1ULL << lane) - 1ULL));
                if (pos < KSEL) sj[pos] = lane + (t << 6);
            }
            emitted += (int)__popcll(m);
        }
#pragma unroll
        for (int t = 0; t < 64; ++t) {
            const bool e_ = (K[t] == P);
            const unsigned long long m = __ballot(e_);
            const int before = (int)__popcll(m & ((1ULL << lane) - 1ULL));
            if (e_ && (emitted + before) < KSEL) sj[emitted + before] = lane + (t << 6);
            emitted += (int)__popcll(m);
        }
        __threadfence_block();
        if (lane < KSEL) jn = sj[lane];
    }

    float s0 = 0.0f, s1 = 0.0f, s2 = 0.0f;
    if (lane < KSEL) {
        idx_out[obase + lane] = jn;
        float cx, cy, cz;
        if (jn >= SURVZ) {
            cx = xb[jn]; cy = xb[NPTS + jn]; cz = xb[2 * NPTS + jn];
        } else {
            const float4 c = pts[jn];
            cx = c.x; cy = c.y; cz = c.z;
        }
        const float xr = cx - q.x, yr = cy - q.y, zr = cz - q.z;
        const float sxy2 = xr * xr + yr * yr;
        const float r2   = sxy2 + zr * zr;
        const float rho  = sqrtf(fmaxf(r2, 1e-20f));
        const float sxy  = sqrtf(fmaxf(sxy2, 1e-20f));
        const bool dr = r2 < 1e-20f;
        const bool dp = sxy2 < 1e-20f;
        const float theta = atan2f(dr ? 0.0f : zr, dr ? 1.0f : sxy);
        const float phi   = atan2f(dp ? 0.0f : yr, dp ? 1.0f : xr);
        sph[obase + lane]             = rho;
        sph[NROWS + obase + lane]     = theta;
        sph[2 * NROWS + obase + lane] = phi;
        s0 = rho; s1 = theta; s2 = phi;
    }

    float mom[9] = {s0, s1, s2, s0 * s0, s0 * s1, s0 * s2, s1 * s1, s1 * s2, s2 * s2};
#pragma unroll
    for (int o = 32; o > 0; o >>= 1) {
#pragma unroll
        for (int m = 0; m < 9; ++m) mom[m] += __shfl_xor(mom[m], o, 64);
    }
    if (lane == 0) {
#pragma unroll
        for (int m = 0; m < 9; ++m) msc[wv * 9 + m] = mom[m];
    }
    __syncthreads();
    if (tid < 9) {
        float t_ = 0.0f;
#pragma unroll
        for (int w = 0; w < 8; ++w) t_ += msc[w * 9 + tid];
        atomicAdd(&accM[tid * 64 + ((blockIdx.y * 512 + blockIdx.x) & 63)], t_);
    }
}

// ---------------------------------------------------------------------------
// Kernel 2: h1 moments (27), grid-stride 4 rows/thread; first 512 blocks also
// transpose x [B,C,N] -> xT [B,N,C].  (R9-exact)
// ---------------------------------------------------------------------------
__global__ __launch_bounds__(256) void p2_k(const float* __restrict__ sph,
                                            const float* __restrict__ x,
                                            float* __restrict__ xT,
                                            const float* __restrict__ W1,
                                            const float* __restrict__ g1,
                                            const float* __restrict__ b1,
                                            const float* __restrict__ accM,
                                            float* __restrict__ acc2) {
    __shared__ float sSum[9];
    __shared__ float sPar[12];
    __shared__ float red[4][27];
    __shared__ float tile[64][65];
    const int tid = threadIdx.x;
    slot_reduce<9>(accM, sSum, tid);
    __syncthreads();
    bn1_params(sSum, W1, g1, b1, sPar, tid);
    __syncthreads();

    float m27[27];
#pragma unroll
    for (int m = 0; m < 27; ++m) m27[m] = 0.0f;
#pragma unroll
    for (int s = 0; s < 4; ++s) {
        const size_t r = (size_t)blockIdx.x * 256 + tid + (size_t)s * P23_STRIDE;
        const float s0 = sph[r], s1 = sph[NROWS + r], s2 = sph[2 * NROWS + r];
        float h1[6];
        mlp_h1(s0, s1, s2, W1, sPar, h1);
        int qq = 6;
#pragma unroll
        for (int a2 = 0; a2 < 6; ++a2) {
            m27[a2] += h1[a2];
#pragma unroll
            for (int b2_ = a2; b2_ < 6; ++b2_) m27[qq++] += h1[a2] * h1[b2_];
        }
    }
#pragma unroll
    for (int o = 32; o > 0; o >>= 1) {
#pragma unroll
        for (int m = 0; m < 27; ++m) m27[m] += __shfl_xor(m27[m], o, 64);
    }
    const int lane = tid & 63, wv = tid >> 6;
    if (lane == 0) {
#pragma unroll
        for (int m = 0; m < 27; ++m) red[wv][m] = m27[m];
    }
    __syncthreads();
    if (tid < 27) {
        const float v = red[0][tid] + red[1][tid] + red[2][tid] + red[3][tid];
        atomicAdd(&acc2[tid * 64 + (blockIdx.x & 63)], v);
    }

    if (blockIdx.x < 512) {
        const int b  = blockIdx.x >> 6;
        const int n0 = (blockIdx.x & 63) << 6;
        const int tx = tid & 63;
        const int ty = tid >> 6;
        const float* xb = x + ((size_t)b << 18);
#pragma unroll
        for (int i = 0; i < 16; ++i) {
            const int c = (i << 2) + ty;
            tile[c][tx] = xb[((size_t)c << 12) + n0 + tx];
        }
        __syncthreads();
        float* ob = xT + ((size_t)b << 18);
#pragma unroll
        for (int i = 0; i < 16; ++i) {
            const int nl = (i << 2) + ty;
            ob[((size_t)(n0 + nl) << 6) + tx] = tile[tx][nl];
        }
    }
}

// ---------------------------------------------------------------------------
// Kernel 3: h2 moments (9) + y3 = W3.h2 store, grid-stride 4 rows/thread.
// (R9-exact)
// ---------------------------------------------------------------------------
__global__ __launch_bounds__(256) void p3_k(const float* __restrict__ sph,
                                            const float* __restrict__ W1,
                                            const float* __restrict__ g1,
                                            const float* __restrict__ b1,
                                            const float* __restrict__ W2,
                                            const float* __restrict__ g2,
                                            const float* __restrict__ b2,
                                            const float* __restrict__ W3,
                                            const float* __restrict__ accM,
                                            const float* __restrict__ acc2,
                                            float* __restrict__ acc3,
                                            float* __restrict__ y3) {
    __shared__ float sSum[27];
    __shared__ float sPar[18];
    __shared__ float red[4][9];
    const int tid = threadIdx.x;
    slot_reduce<9>(accM, sSum, tid);
    __syncthreads();
    bn1_params(sSum, W1, g1, b1, sPar, tid);
    __syncthreads();
    slot_reduce<27>(acc2, sSum, tid);
    __syncthreads();
    bn2_params(sSum, W2, g2, b2, sPar, tid);
    __syncthreads();

    const float w30 = W3[0], w31 = W3[1], w32 = W3[2];

    float m9[9];
#pragma unroll
    for (int m = 0; m < 9; ++m) m9[m] = 0.0f;
#pragma unroll
    for (int s = 0; s < 4; ++s) {
        const size_t r = (size_t)blockIdx.x * 256 + tid + (size_t)s * P23_STRIDE;
        const float s0 = sph[r], s1 = sph[NROWS + r], s2 = sph[2 * NROWS + r];
        float h1[6], h2[3];
        mlp_h1(s0, s1, s2, W1, sPar, h1);
        mlp_h2(h1, W2, sPar, h2);
        y3[r] = fmaf(w30, h2[0], fmaf(w31, h2[1], w32 * h2[2]));
        m9[0] += h2[0]; m9[1] += h2[1]; m9[2] += h2[2];
        m9[3] += h2[0] * h2[0]; m9[4] += h2[0] * h2[1]; m9[5] += h2[0] * h2[2];
        m9[6] += h2[1] * h2[1]; m9[7] += h2[1] * h2[2]; m9[8] += h2[2] * h2[2];
    }
#pragma unroll
    for (int o = 32; o > 0; o >>= 1) {
#pragma unroll
        for (int m = 0; m < 9; ++m) m9[m] += __shfl_xor(m9[m], o, 64);
    }
    const int lane = tid & 63, wv = tid >> 6;
    if (lane == 0) {
#pragma unroll
        for (int m = 0; m < 9; ++m) red[wv][m] = m9[m];
    }
    __syncthreads();
    if (tid < 9) {
        const float v = red[0][tid] + red[1][tid] + red[2][tid] + red[3][tid];
        atomicAdd(&acc3[tid * 64 + (blockIdx.x & 63)], v);
    }
}

// ---------------------------------------------------------------------------
// Kernel 4: att = lrelu(BN3(y3)), softmax, gather, residual out.
// R12: gather loop 3-way ILP (three independent FMA chains over 30 neighbors).
// ---------------------------------------------------------------------------
__global__ __launch_bounds__(256) void p4_k(const float* __restrict__ y3,
                                            const int* __restrict__ idx,
                                            const float* __restrict__ x,
                                            const float* __restrict__ xT,
                                            const float* __restrict__ W3,
                                            const float* __restrict__ g3,
                                            const float* __restrict__ b3,
                                            const float* __restrict__ acc3,
                                            float* __restrict__ out) {
    __shared__ float sSum[9];
    __shared__ float sPar[2];
    __shared__ float agg[32][65];
    const int tid = threadIdx.x;
    slot_reduce<9>(acc3, sSum, tid);
    __syncthreads();
    bn3_params(sSum, W3, g3, b3, sPar, tid);
    __syncthreads();
    const float sc3 = sPar[0], tb3 = sPar[1];

    const int lane = tid & 63, wv = tid >> 6;
    const int b    = blockIdx.x & 7;         // XCD swizzle: one batch per XCD
    const int n0   = (blockIdx.x >> 3) << 5; // 32 consecutive points within batch
    const int p0   = (b << 12) + n0;
    const float* xTb = xT + ((size_t)b << 18);

    for (int i = 0; i < 8; ++i) {
        const int pl = (wv << 3) + i;
        const int p  = p0 + pl;
        float a = -3.4e38f;
        int jn = 0;
        if (lane < KSEL) {
            const size_t r = (size_t)p * KSEL + lane;
            const float z = fmaf(y3[r], sc3, tb3);
            a = z >= 0.0f ? z : 0.2f * z;
            jn = idx[r];
        }
        float mx = a;
#pragma unroll
        for (int o = 32; o > 0; o >>= 1) mx = fmaxf(mx, __shfl_xor(mx, o, 64));
        const float e = (lane < KSEL) ? expf(a - mx) : 0.0f;
        float se = e;
#pragma unroll
        for (int o = 32; o > 0; o >>= 1) se += __shfl_xor(se, o, 64);
        const float w = e / se;

        float acc0 = 0.0f, acc1 = 0.0f, acc2_ = 0.0f;
#pragma unroll
        for (int t = 0; t < KSEL; t += 3) {
            const int   j0 = __shfl(jn, t, 64);
            const float w0 = __shfl(w, t, 64);
            const int   j1 = __shfl(jn, t + 1, 64);
            const float w1 = __shfl(w, t + 1, 64);
            const int   j2 = __shfl(jn, t + 2, 64);
            const float w2 = __shfl(w, t + 2, 64);
            acc0  = fmaf(w0, xTb[((size_t)j0 << 6) + lane], acc0);
            acc1  = fmaf(w1, xTb[((size_t)j1 << 6) + lane], acc1);
            acc2_ = fmaf(w2, xTb[((size_t)j2 << 6) + lane], acc2_);
        }
        agg[pl][lane] = acc0 + acc1 + acc2_;
    }
    __syncthreads();

    const float* xb = x + ((size_t)b << 18);
    float* ob = out + ((size_t)b << 18);
    const int nl = tid & 31, cb = tid >> 5;
#pragma unroll
    for (int i = 0; i < 8; ++i) {
        const int c = (i << 3) + cb;
        const size_t off = ((size_t)c << 12) + n0 + nl;
        ob[off] = xb[off] + agg[nl][c];
    }
}

// ---------------------------------------------------------------------------
extern "C" void kernel_launch(void* const* d_in, const int* in_sizes, int n_in,
                              void* d_out, int out_size, void* d_ws, size_t ws_size,
                              hipStream_t stream) {
    const float* x_loc = (const float*)d_in[0];
    const float* x     = (const float*)d_in[1];
    const float* W1    = (const float*)d_in[2];
    const float* g1    = (const float*)d_in[3];
    const float* b1    = (const float*)d_in[4];
    const float* W2    = (const float*)d_in[5];
    const float* g2    = (const float*)d_in[6];
    const float* b2    = (const float*)d_in[7];
    const float* W3    = (const float*)d_in[8];
    const float* g3    = (const float*)d_in[9];
    const float* b3    = (const float*)d_in[10];
    float* out = (float*)d_out;

    float* accM = (float*)d_ws;                 //  9*64
    float* acc2 = accM + 576;                   // 27*64
    float* acc3 = acc2 + 1728;                  //  9*64  (acc region = 2880 floats)
    float* sph  = acc3 + 576;                   // 3*NROWS
    int*   idx  = (int*)(sph + 3 * (size_t)NROWS);
    float* y3   = (float*)(idx + NROWS);        // NROWS
    float* xT   = y3 + NROWS;                   // B*N*C

    hipMemsetAsync(d_ws, 0, 11520, stream);

    knn_k<<<dim3(NPTS / 8, NB), 512, 0, stream>>>(x_loc, idx, sph, accM);
    p2_k<<<P23_BLOCKS, 256, 0, stream>>>(sph, x, xT, W1, g1, b1, accM, acc2);
    p3_k<<<P23_BLOCKS, 256, 0, stream>>>(sph, W1, g1, b1, W2, g2, b2, W3, accM, acc2, acc3, y3);
    p4_k<<<(NB * NPTS) / 32, 256, 0, stream>>>(y3, idx, x, xT, W3, g3, b3, acc3, out);
}